// Round 4
// baseline (189.850 us; speedup 1.0000x reference)
//
#include <hip/hip_runtime.h>

typedef __attribute__((ext_vector_type(8))) short short8;
typedef __bf16 bf16x8 __attribute__((ext_vector_type(8)));
typedef __attribute__((ext_vector_type(4))) float f32x4;

static constexpr int Bn = 4, Cn = 256, Nn = 2048, CGn = 64;
static constexpr float EPSf = 1e-5f;
static constexpr float LOG2E = 1.44269504088896f;

#define DEV __device__ __forceinline__

DEV unsigned short f2bf(float f) {
  return __builtin_bit_cast(unsigned short, (__bf16)f);
}

DEV unsigned pk2bf(float a, float b) {
  return (unsigned)f2bf(a) | ((unsigned)f2bf(b) << 16);
}

DEV f32x4 mfma16(short8 a, short8 b, f32x4 c) {
  return __builtin_amdgcn_mfma_f32_16x16x32_bf16(
      __builtin_bit_cast(bf16x8, a), __builtin_bit_cast(bf16x8, b), c, 0, 0, 0);
}

DEV short8 ld8(const unsigned short* p) { return *(const short8*)p; }

// ---------------- K0: convert weights to bf16 ----------------
__global__ __launch_bounds__(256) void k_wconv(
    const float* __restrict__ Wt, const float* __restrict__ Wp, const float* __restrict__ Wg,
    const float* __restrict__ Wz, unsigned short* __restrict__ wtb, unsigned short* __restrict__ wpb,
    unsigned short* __restrict__ wgb, unsigned short* __restrict__ wzb) {
  int i = blockIdx.x * 256 + threadIdx.x;  // grid covers 65536
  wtb[i] = f2bf(Wt[i]);
  wpb[i] = f2bf(Wp[i]);
  wgb[i] = f2bf(Wg[i]);
  if (i < 16384) wzb[i] = f2bf(Wz[i]);
}

// ---------------- KT: x,y -> bf16 transposed [b][h][c] ----------------
__global__ __launch_bounds__(256) void k_transpose(
    const float* __restrict__ x, const float* __restrict__ y,
    unsigned short* __restrict__ xt, unsigned short* __restrict__ yt) {
  int idx = blockIdx.x * 256 + threadIdx.x;
  size_t f = (size_t)idx * 4;
  int h = (int)(f & (Nn - 1));
  int c = (int)((f >> 11) & (Cn - 1));
  int b = (int)(f >> 19);
  float4 xv = *(const float4*)(x + f);
  float4 yv = *(const float4*)(y + f);
  size_t ob = ((size_t)b * Nn + h) * Cn + c;
  xt[ob] = f2bf(xv.x); xt[ob + Cn] = f2bf(xv.y);
  xt[ob + 2 * Cn] = f2bf(xv.z); xt[ob + 3 * Cn] = f2bf(xv.w);
  yt[ob] = f2bf(yv.x); yt[ob + Cn] = f2bf(yv.y);
  yt[ob + 2 * Cn] = f2bf(yv.z); yt[ob + 3 * Cn] = f2bf(yv.w);
}

// ---------------- K1: channel-mix GEMMs (LDS-free) ----------------
// op0: P(queries)=Wp*x ; op1: T(values)=Wt*y ; op2: Gt(keys, transposed,
// scaled by log2(e) so attention scores land in the exp2 domain)=Wg*y
__global__ __launch_bounds__(256) void k_mix(
    const unsigned short* __restrict__ xt, const unsigned short* __restrict__ yt,
    const unsigned short* __restrict__ wpb, const unsigned short* __restrict__ wtb,
    const unsigned short* __restrict__ wgb,
    unsigned short* __restrict__ P, unsigned short* __restrict__ T,
    unsigned short* __restrict__ Gt) {
  int t = threadIdx.x, lane = t & 63, w = t >> 6;
  int q = lane >> 4, li = lane & 15;
  int zb = blockIdx.z;  // 12
  int b = zb & 3, op = zb >> 2;
  const unsigned short* in = (op == 0 ? xt : yt) + (size_t)b * Nn * Cn;
  const unsigned short* W = (op == 0 ? wpb : (op == 1 ? wtb : wgb));
  int p0 = (blockIdx.y * 4 + w) * 32;
  int h0 = blockIdx.x * 64;
  f32x4 acc[2][4] = {};
#pragma unroll
  for (int kk = 0; kk < 8; ++kk) {
    int cb = kk * 32 + q * 8;
    short8 a0 = ld8(W + (p0 + li) * 256 + cb);
    short8 a1 = ld8(W + (p0 + 16 + li) * 256 + cb);
#pragma unroll
    for (int nt = 0; nt < 4; ++nt) {
      short8 bf = ld8(in + (size_t)(h0 + nt * 16 + li) * 256 + cb);
      acc[0][nt] = mfma16(a0, bf, acc[0][nt]);
      acc[1][nt] = mfma16(a1, bf, acc[1][nt]);
    }
  }
  if (op < 2) {
    unsigned short* dst = (op == 0 ? P : T) + (size_t)b * Cn * Nn;
#pragma unroll
    for (int mt = 0; mt < 2; ++mt)
#pragma unroll
      for (int nt = 0; nt < 4; ++nt)
#pragma unroll
        for (int r = 0; r < 4; ++r)
          dst[(size_t)(p0 + mt * 16 + q * 4 + r) * Nn + h0 + nt * 16 + li] =
              f2bf(acc[mt][nt][r]);
  } else {
#pragma unroll
    for (int mt = 0; mt < 2; ++mt)
#pragma unroll
      for (int nt = 0; nt < 4; ++nt)
#pragma unroll
        for (int r = 0; r < 4; ++r) {
          int c = p0 + mt * 16 + q * 4 + r;
          int h = h0 + nt * 16 + li;
          Gt[(((size_t)(b * 4 + (c >> 6)) * Nn + h) << 6) + (c & 63)] =
              f2bf(acc[mt][nt][r] * LOG2E);
        }
  }
}

// ---------------- K3: attention, 4 waves/block split the j-range ----------------
// No-max softmax => per-wave partial (O, rs) just ADD across waves.
// XCD-pinned decode: bid&7 -> XCD; each XCD owns 2 (b,g) heads so K/V/Q stay
// L2-resident (~1.5MB < 4MB). LDS P-staging XOR-swizzled (row stride 160B).
__global__ __launch_bounds__(256, 8) void k_attn(
    const unsigned short* __restrict__ Pq, const unsigned short* __restrict__ Tv,
    const unsigned short* __restrict__ Gt, unsigned short* __restrict__ OT) {
  __shared__ __align__(16) char smem[17664];
  unsigned short* PL = (unsigned short*)smem;       // [4][16][80] ushort (10240B)
  float* LO = (float*)smem;                         // [4][16][68] f32 (17408B), after barrier
  float* LR = (float*)(smem + 17408);               // [4][16] f32

  int t = threadIdx.x, lane = t & 63, w = t >> 6;
  int q = lane >> 4, li = lane & 15;
  int bid = blockIdx.x;
  int xcd = bid & 7, slot = bid >> 3;
  int bg = xcd * 2 + (slot >> 7);
  int i0 = (slot & 127) * 16;
  int b = bg >> 2, g = bg & 3;
  const unsigned short* Q = Pq + (size_t)(b * Cn + g * CGn) * Nn;
  const unsigned short* V = Tv + (size_t)(b * Cn + g * CGn) * Nn;
  const unsigned short* Kk = Gt + (size_t)bg * Nn * CGn;

  short8 qf[2];
#pragma unroll
  for (int cs = 0; cs < 2; ++cs) {
    short8 v;
#pragma unroll
    for (int e = 0; e < 8; ++e)
      v[e] = (short)Q[(size_t)(cs * 32 + q * 8 + e) * Nn + i0 + li];
    qf[cs] = v;
  }
  f32x4 O[4] = {};
  float rs = 0.f;
  int wbase = w * 1280;  // 16*80 ushorts per wave
  int swz = (li & 7) << 3;

  for (int jt8 = 0; jt8 < 8; ++jt8) {
    int j0 = w * 512 + jt8 * 64;
    f32x4 F[4] = {};
#pragma unroll
    for (int jt = 0; jt < 4; ++jt) {
      const unsigned short* kp = Kk + (size_t)(j0 + jt * 16 + li) * 64 + q * 8;
      F[jt] = mfma16(ld8(kp), qf[0], F[jt]);
      F[jt] = mfma16(ld8(kp + 32), qf[1], F[jt]);
    }
#pragma unroll
    for (int jt = 0; jt < 4; ++jt) {
      float e0 = __builtin_amdgcn_exp2f(F[jt][0]);
      float e1 = __builtin_amdgcn_exp2f(F[jt][1]);
      float e2 = __builtin_amdgcn_exp2f(F[jt][2]);
      float e3 = __builtin_amdgcn_exp2f(F[jt][3]);
      rs += (e0 + e1) + (e2 + e3);
      *(uint2*)&PL[wbase + ((li * 80 + jt * 16 + q * 4) ^ swz)] =
          make_uint2(pk2bf(e0, e1), pk2bf(e2, e3));
    }
#pragma unroll
    for (int cs = 0; cs < 2; ++cs) {
      short8 pf = *(const short8*)&PL[wbase + ((li * 80 + cs * 32 + q * 8) ^ swz)];
#pragma unroll
      for (int ct = 0; ct < 4; ++ct) {
        short8 vf = ld8(V + (size_t)(ct * 16 + li) * Nn + j0 + cs * 32 + q * 8);
        O[ct] = mfma16(pf, vf, O[ct]);
      }
    }
  }
  // per-wave denominator partial for q-row li (sum across the 4 q-lane-groups)
  rs += __shfl_xor(rs, 16);
  rs += __shfl_xor(rs, 32);
  __syncthreads();  // P areas dead; LDS becomes the O/rs reduce buffer
#pragma unroll
  for (int ct = 0; ct < 4; ++ct)
#pragma unroll
    for (int r = 0; r < 4; ++r)
      LO[(w * 16 + q * 4 + r) * 68 + ct * 16 + li] = O[ct][r];
  if (q == 0) LR[w * 16 + li] = rs;
  __syncthreads();
  // final: thread t -> row i = t>>4, col block c4 = t&15
  int i = t >> 4, c4 = t & 15;
  f32x4 acc = {};
#pragma unroll
  for (int wv = 0; wv < 4; ++wv) {
    f32x4 part = *(const f32x4*)&LO[(wv * 16 + i) * 68 + c4 * 4];
    acc += part;
  }
  float den = LR[i] + LR[16 + i] + LR[32 + i] + LR[48 + i];
  float rinv = 1.f / den;
  unsigned short* op = OT + (size_t)bg * Nn * CGn;
  *(uint2*)&op[(size_t)(i0 + i) * 64 + c4 * 4] =
      make_uint2(pk2bf(acc[0] * rinv, acc[1] * rinv),
                 pk2bf(acc[2] * rinv, acc[3] * rinv));
}

// ---------------- K4: grouped 1x1 conv + group sum/sumsq ----------------
__global__ __launch_bounds__(256) void k_zconv(
    const unsigned short* __restrict__ wzb, const unsigned short* __restrict__ OT,
    float* __restrict__ Z, float* __restrict__ SUMS) {
  int t = threadIdx.x, lane = t & 63, w = t >> 6;
  int q = lane >> 4, li = lane & 15;
  int bg = blockIdx.y;
  int b = bg >> 2, g = bg & 3;
  int i0 = blockIdx.x * 256 + w * 64;
  const unsigned short* Ws = wzb + g * 64 * 64;
  const unsigned short* Ob = OT + (size_t)bg * Nn * 64;
  f32x4 acc[4][4] = {};
#pragma unroll
  for (int cs = 0; cs < 2; ++cs) {
    short8 af[4];
#pragma unroll
    for (int mt = 0; mt < 4; ++mt)
      af[mt] = ld8(Ws + (mt * 16 + li) * 64 + cs * 32 + q * 8);
#pragma unroll
    for (int nt = 0; nt < 4; ++nt) {
      short8 bf = ld8(Ob + (size_t)(i0 + nt * 16 + li) * 64 + cs * 32 + q * 8);
#pragma unroll
      for (int mt = 0; mt < 4; ++mt) acc[mt][nt] = mfma16(af[mt], bf, acc[mt][nt]);
    }
  }
  float s1 = 0.f, s2 = 0.f;
  float* zb = Z + (size_t)b * Cn * Nn + (size_t)g * 64 * Nn;
#pragma unroll
  for (int mt = 0; mt < 4; ++mt)
#pragma unroll
    for (int nt = 0; nt < 4; ++nt)
#pragma unroll
      for (int r = 0; r < 4; ++r) {
        float v = acc[mt][nt][r];
        s1 += v; s2 += v * v;
        zb[(size_t)(mt * 16 + q * 4 + r) * Nn + i0 + nt * 16 + li] = v;
      }
#pragma unroll
  for (int off = 32; off; off >>= 1) {
    s1 += __shfl_xor(s1, off);
    s2 += __shfl_xor(s2, off);
  }
  if (lane == 0) {
    atomicAdd(&SUMS[bg * 2], s1);
    atomicAdd(&SUMS[bg * 2 + 1], s2);
  }
}

// ---------------- K5: GroupNorm + affine + residual ----------------
__global__ __launch_bounds__(256) void k_norm(
    const float* __restrict__ Z, const float* __restrict__ x,
    const float* __restrict__ gamma, const float* __restrict__ beta,
    const float* __restrict__ SUMS, float* __restrict__ out) {
  int idx = blockIdx.x * 256 + threadIdx.x;
  size_t f = (size_t)idx * 4;
  int c = (int)((f >> 11) & (Cn - 1));
  int b = (int)(f >> 19);
  int bg = b * 4 + (c >> 6);
  const float inv = 1.f / 131072.f;
  float mean = SUMS[bg * 2] * inv;
  float var = SUMS[bg * 2 + 1] * inv - mean * mean;
  float rstd = rsqrtf(var + EPSf);
  float ga = gamma[c] * rstd;
  float be = beta[c] - mean * ga;
  float4 zv = *(const float4*)(Z + f);
  float4 xv = *(const float4*)(x + f);
  float4 o;
  o.x = zv.x * ga + be + xv.x;
  o.y = zv.y * ga + be + xv.y;
  o.z = zv.z * ga + be + xv.z;
  o.w = zv.w * ga + be + xv.w;
  *(float4*)(out + f) = o;
}

extern "C" void kernel_launch(void* const* d_in, const int* in_sizes, int n_in,
                              void* d_out, int out_size, void* d_ws, size_t ws_size,
                              hipStream_t stream) {
  (void)in_sizes; (void)n_in; (void)out_size; (void)ws_size;
  const float* x = (const float*)d_in[0];
  const float* y = (const float*)d_in[1];
  const float* Wt = (const float*)d_in[2];
  const float* Wp = (const float*)d_in[3];
  const float* Wg = (const float*)d_in[4];
  const float* Wz = (const float*)d_in[5];
  const float* gamma = (const float*)d_in[6];
  const float* beta = (const float*)d_in[7];
  float* out = (float*)d_out;
  char* ws = (char*)d_ws;
  unsigned short* wpb = (unsigned short*)(ws + 0);
  unsigned short* wtb = (unsigned short*)(ws + 131072);
  unsigned short* wgb = (unsigned short*)(ws + 262144);
  unsigned short* wzb = (unsigned short*)(ws + 393216);
  unsigned short* xt  = (unsigned short*)(ws + 425984);    // 4MB
  unsigned short* yt  = (unsigned short*)(ws + 4620288);   // 4MB
  unsigned short* Pq  = (unsigned short*)(ws + 8814592);   // 4MB
  unsigned short* Tv  = (unsigned short*)(ws + 13008896);  // 4MB
  unsigned short* Gt  = (unsigned short*)(ws + 17203200);  // 4MB
  unsigned short* OT  = (unsigned short*)(ws + 21397504);  // 4MB
  float* Z    = (float*)(ws + 425984);   // overlaps xt/yt (dead after k_mix)
  float* SUMS = (float*)(ws + 25591808);

  k_wconv<<<256, 256, 0, stream>>>(Wt, Wp, Wg, Wz, wtb, wpb, wgb, wzb);
  k_transpose<<<2048, 256, 0, stream>>>(x, y, xt, yt);
  k_mix<<<dim3(32, 2, 12), 256, 0, stream>>>(xt, yt, wpb, wtb, wgb, Pq, Tv, Gt);
  k_attn<<<2048, 256, 0, stream>>>(Pq, Tv, Gt, OT);
  (void)hipMemsetAsync(SUMS, 0, 128, stream);
  k_zconv<<<dim3(8, 16), 256, 0, stream>>>(wzb, OT, Z, SUMS);
  k_norm<<<2048, 256, 0, stream>>>(Z, x, gamma, beta, SUMS, out);
}

// Round 5
// 106.688 us; speedup vs baseline: 1.7795x; 1.7795x over previous
//
#include <hip/hip_runtime.h>

typedef __attribute__((ext_vector_type(8))) short short8;
typedef __bf16 bf16x8 __attribute__((ext_vector_type(8)));
typedef __attribute__((ext_vector_type(4))) float f32x4;

static constexpr int Bn = 4, Cn = 256, Nn = 2048, CGn = 64;
static constexpr float EPSf = 1e-5f;
static constexpr float LOG2E = 1.44269504088896f;

#define DEV __device__ __forceinline__

DEV unsigned short f2bf(float f) {
  return __builtin_bit_cast(unsigned short, (__bf16)f);
}

DEV unsigned pk2bf(float a, float b) {
  return (unsigned)f2bf(a) | ((unsigned)f2bf(b) << 16);
}

DEV f32x4 mfma16(short8 a, short8 b, f32x4 c) {
  return __builtin_amdgcn_mfma_f32_16x16x32_bf16(
      __builtin_bit_cast(bf16x8, a), __builtin_bit_cast(bf16x8, b), c, 0, 0, 0);
}

DEV short8 ld8(const unsigned short* p) { return *(const short8*)p; }

// ---------------- K0: convert weights to bf16 ----------------
__global__ __launch_bounds__(256) void k_wconv(
    const float* __restrict__ Wt, const float* __restrict__ Wp, const float* __restrict__ Wg,
    const float* __restrict__ Wz, unsigned short* __restrict__ wtb, unsigned short* __restrict__ wpb,
    unsigned short* __restrict__ wgb, unsigned short* __restrict__ wzb) {
  int i = blockIdx.x * 256 + threadIdx.x;  // grid covers 65536
  wtb[i] = f2bf(Wt[i]);
  wpb[i] = f2bf(Wp[i]);
  wgb[i] = f2bf(Wg[i]);
  if (i < 16384) wzb[i] = f2bf(Wz[i]);
}

// ---------------- KT: x,y -> bf16 transposed [b][h][c] ----------------
__global__ __launch_bounds__(256) void k_transpose(
    const float* __restrict__ x, const float* __restrict__ y,
    unsigned short* __restrict__ xt, unsigned short* __restrict__ yt) {
  int idx = blockIdx.x * 256 + threadIdx.x;
  size_t f = (size_t)idx * 4;
  int h = (int)(f & (Nn - 1));
  int c = (int)((f >> 11) & (Cn - 1));
  int b = (int)(f >> 19);
  float4 xv = *(const float4*)(x + f);
  float4 yv = *(const float4*)(y + f);
  size_t ob = ((size_t)b * Nn + h) * Cn + c;
  xt[ob] = f2bf(xv.x); xt[ob + Cn] = f2bf(xv.y);
  xt[ob + 2 * Cn] = f2bf(xv.z); xt[ob + 3 * Cn] = f2bf(xv.w);
  yt[ob] = f2bf(yv.x); yt[ob + Cn] = f2bf(yv.y);
  yt[ob + 2 * Cn] = f2bf(yv.z); yt[ob + 3 * Cn] = f2bf(yv.w);
}

// ---------------- K1: channel-mix GEMMs (LDS-free) ----------------
// op0: P(queries)=Wp*x ; op1: T(values)=Wt*y ; op2: Gt(keys, transposed,
// scaled by log2(e) so attention scores land in the exp2 domain)=Wg*y
__global__ __launch_bounds__(256) void k_mix(
    const unsigned short* __restrict__ xt, const unsigned short* __restrict__ yt,
    const unsigned short* __restrict__ wpb, const unsigned short* __restrict__ wtb,
    const unsigned short* __restrict__ wgb,
    unsigned short* __restrict__ P, unsigned short* __restrict__ T,
    unsigned short* __restrict__ Gt) {
  int t = threadIdx.x, lane = t & 63, w = t >> 6;
  int q = lane >> 4, li = lane & 15;
  int zb = blockIdx.z;  // 12
  int b = zb & 3, op = zb >> 2;
  const unsigned short* in = (op == 0 ? xt : yt) + (size_t)b * Nn * Cn;
  const unsigned short* W = (op == 0 ? wpb : (op == 1 ? wtb : wgb));
  int p0 = (blockIdx.y * 4 + w) * 32;
  int h0 = blockIdx.x * 64;
  f32x4 acc[2][4] = {};
#pragma unroll
  for (int kk = 0; kk < 8; ++kk) {
    int cb = kk * 32 + q * 8;
    short8 a0 = ld8(W + (p0 + li) * 256 + cb);
    short8 a1 = ld8(W + (p0 + 16 + li) * 256 + cb);
#pragma unroll
    for (int nt = 0; nt < 4; ++nt) {
      short8 bf = ld8(in + (size_t)(h0 + nt * 16 + li) * 256 + cb);
      acc[0][nt] = mfma16(a0, bf, acc[0][nt]);
      acc[1][nt] = mfma16(a1, bf, acc[1][nt]);
    }
  }
  if (op < 2) {
    unsigned short* dst = (op == 0 ? P : T) + (size_t)b * Cn * Nn;
#pragma unroll
    for (int mt = 0; mt < 2; ++mt)
#pragma unroll
      for (int nt = 0; nt < 4; ++nt)
#pragma unroll
        for (int r = 0; r < 4; ++r)
          dst[(size_t)(p0 + mt * 16 + q * 4 + r) * Nn + h0 + nt * 16 + li] =
              f2bf(acc[mt][nt][r]);
  } else {
#pragma unroll
    for (int mt = 0; mt < 2; ++mt)
#pragma unroll
      for (int nt = 0; nt < 4; ++nt)
#pragma unroll
        for (int r = 0; r < 4; ++r) {
          int c = p0 + mt * 16 + q * 4 + r;
          int h = h0 + nt * 16 + li;
          Gt[(((size_t)(b * 4 + (c >> 6)) * Nn + h) << 6) + (c & 63)] =
              f2bf(acc[mt][nt][r] * LOG2E);
        }
  }
}

// ---------------- K3: attention, LDS-staged K/V shared by 4 waves ----------------
// Block = 4 waves, 64 q-rows (wave w owns rows i0+w*16..+15), sweeps all j.
// Per 64-j tile: stage K(8KB)+V(8KB) to LDS with COALESCED global loads
// (K: 2KB contiguous per wave-instr; V: 128B per 4 lanes), prefetching the
// next tile into registers so L2 latency hides under compute. All LDS b128
// accesses use a 16B-slot XOR swizzle (slot ^= row&7) -> uniform bank use.
// No-max softmax (scores bounded), XCD-pinned heads for L2 residency.
__global__ __launch_bounds__(256) void k_attn(
    const unsigned short* __restrict__ Pq, const unsigned short* __restrict__ Tv,
    const unsigned short* __restrict__ Gt, unsigned short* __restrict__ OT) {
  __shared__ __align__(16) unsigned short lds[12288];  // Ks[4096] Vs[4096] PL[4096]

  int t = threadIdx.x, lane = t & 63, w = t >> 6;
  int q = lane >> 4, li = lane & 15;
  int bid = blockIdx.x;
  int xcd = bid & 7, slot = bid >> 3;           // 512 blocks: 64 slots/XCD
  int bg = xcd * 2 + (slot >> 5);               // 2 heads per XCD -> L2-resident
  int i0 = (slot & 31) * 64;
  int b = bg >> 2, g = bg & 3;
  const unsigned short* Q = Pq + (size_t)(b * Cn + g * CGn) * Nn;
  const unsigned short* V = Tv + (size_t)(b * Cn + g * CGn) * Nn;
  const unsigned short* Kk = Gt + (size_t)bg * Nn * CGn;

  int iw = i0 + w * 16;  // this wave's 16 q-rows
  short8 qf[2];
#pragma unroll
  for (int cs = 0; cs < 2; ++cs) {
    short8 v;
#pragma unroll
    for (int e = 0; e < 8; ++e)
      v[e] = (short)Q[(size_t)(cs * 32 + q * 8 + e) * Nn + iw + li];
    qf[cs] = v;
  }
  f32x4 O[4] = {};
  float rs = 0.f;

  // staging: thread t owns chunks c=2t,2t+1 (16B each) of the 64x64 tiles
  int srow = t >> 2;          // both chunks in same row
  int soff0 = (t & 3) * 2;    // 16B-slot 0..7
  short8 kst[2], vst[2];
#pragma unroll
  for (int u = 0; u < 2; ++u) {
    kst[u] = ld8(Kk + (size_t)srow * 64 + (soff0 + u) * 8);
    vst[u] = ld8(V + (size_t)srow * Nn + (soff0 + u) * 8);
  }

  for (int jt32 = 0; jt32 < 32; ++jt32) {
    __syncthreads();  // previous tile's LDS reads complete
#pragma unroll
    for (int u = 0; u < 2; ++u) {
      int sl = (soff0 + u) ^ (srow & 7);
      *(short8*)&lds[srow * 64 + sl * 8] = kst[u];
      *(short8*)&lds[4096 + srow * 64 + sl * 8] = vst[u];
    }
    if (jt32 < 31) {
      int j1 = (jt32 + 1) * 64;
#pragma unroll
      for (int u = 0; u < 2; ++u) {
        kst[u] = ld8(Kk + (size_t)(j1 + srow) * 64 + (soff0 + u) * 8);
        vst[u] = ld8(V + (size_t)srow * Nn + j1 + (soff0 + u) * 8);
      }
    }
    __syncthreads();  // staged tile visible

    f32x4 F[4] = {};
#pragma unroll
    for (int jt = 0; jt < 4; ++jt) {
      int row = jt * 16 + li;
      short8 k0 = *(const short8*)&lds[row * 64 + ((q) ^ (row & 7)) * 8];
      short8 k1 = *(const short8*)&lds[row * 64 + ((4 + q) ^ (row & 7)) * 8];
      F[jt] = mfma16(k0, qf[0], F[jt]);
      F[jt] = mfma16(k1, qf[1], F[jt]);
    }
#pragma unroll
    for (int jt = 0; jt < 4; ++jt) {
      float e0 = __builtin_amdgcn_exp2f(F[jt][0]);
      float e1 = __builtin_amdgcn_exp2f(F[jt][1]);
      float e2 = __builtin_amdgcn_exp2f(F[jt][2]);
      float e3 = __builtin_amdgcn_exp2f(F[jt][3]);
      rs += (e0 + e1) + (e2 + e3);
      // P[row=li][bytes jt*32+q*8]: slot=jt*2+(q>>1), sub=(q&1)*8B
      *(uint2*)&lds[8192 + (w * 16 + li) * 64 +
                    ((jt * 2 + (q >> 1)) ^ (li & 7)) * 8 + (q & 1) * 4] =
          make_uint2(pk2bf(e0, e1), pk2bf(e2, e3));
    }
#pragma unroll
    for (int cs = 0; cs < 2; ++cs) {
      short8 pf = *(const short8*)&lds[8192 + (w * 16 + li) * 64 +
                                       ((cs * 4 + q) ^ (li & 7)) * 8];
#pragma unroll
      for (int ct = 0; ct < 4; ++ct) {
        int row = ct * 16 + li;
        short8 vf =
            *(const short8*)&lds[4096 + row * 64 + ((cs * 4 + q) ^ (row & 7)) * 8];
        O[ct] = mfma16(pf, vf, O[ct]);
      }
    }
  }
  rs += __shfl_xor(rs, 16);
  rs += __shfl_xor(rs, 32);
  float r0 = 1.f / __shfl(rs, q * 4 + 0);
  float r1 = 1.f / __shfl(rs, q * 4 + 1);
  float r2 = 1.f / __shfl(rs, q * 4 + 2);
  float r3 = 1.f / __shfl(rs, q * 4 + 3);
  unsigned short* op = OT + (size_t)bg * Nn * CGn;
#pragma unroll
  for (int ct = 0; ct < 4; ++ct) {
    op[(size_t)(iw + q * 4 + 0) * 64 + ct * 16 + li] = f2bf(O[ct][0] * r0);
    op[(size_t)(iw + q * 4 + 1) * 64 + ct * 16 + li] = f2bf(O[ct][1] * r1);
    op[(size_t)(iw + q * 4 + 2) * 64 + ct * 16 + li] = f2bf(O[ct][2] * r2);
    op[(size_t)(iw + q * 4 + 3) * 64 + ct * 16 + li] = f2bf(O[ct][3] * r3);
  }
}

// ---------------- K4: grouped 1x1 conv + group sum/sumsq ----------------
__global__ __launch_bounds__(256) void k_zconv(
    const unsigned short* __restrict__ wzb, const unsigned short* __restrict__ OT,
    float* __restrict__ Z, float* __restrict__ SUMS) {
  int t = threadIdx.x, lane = t & 63, w = t >> 6;
  int q = lane >> 4, li = lane & 15;
  int bg = blockIdx.y;
  int b = bg >> 2, g = bg & 3;
  int i0 = blockIdx.x * 256 + w * 64;
  const unsigned short* Ws = wzb + g * 64 * 64;
  const unsigned short* Ob = OT + (size_t)bg * Nn * 64;
  f32x4 acc[4][4] = {};
#pragma unroll
  for (int cs = 0; cs < 2; ++cs) {
    short8 af[4];
#pragma unroll
    for (int mt = 0; mt < 4; ++mt)
      af[mt] = ld8(Ws + (mt * 16 + li) * 64 + cs * 32 + q * 8);
#pragma unroll
    for (int nt = 0; nt < 4; ++nt) {
      short8 bf = ld8(Ob + (size_t)(i0 + nt * 16 + li) * 64 + cs * 32 + q * 8);
#pragma unroll
      for (int mt = 0; mt < 4; ++mt) acc[mt][nt] = mfma16(af[mt], bf, acc[mt][nt]);
    }
  }
  float s1 = 0.f, s2 = 0.f;
  float* zb = Z + (size_t)b * Cn * Nn + (size_t)g * 64 * Nn;
#pragma unroll
  for (int mt = 0; mt < 4; ++mt)
#pragma unroll
    for (int nt = 0; nt < 4; ++nt)
#pragma unroll
      for (int r = 0; r < 4; ++r) {
        float v = acc[mt][nt][r];
        s1 += v; s2 += v * v;
        zb[(size_t)(mt * 16 + q * 4 + r) * Nn + i0 + nt * 16 + li] = v;
      }
#pragma unroll
  for (int off = 32; off; off >>= 1) {
    s1 += __shfl_xor(s1, off);
    s2 += __shfl_xor(s2, off);
  }
  if (lane == 0) {
    atomicAdd(&SUMS[bg * 2], s1);
    atomicAdd(&SUMS[bg * 2 + 1], s2);
  }
}

// ---------------- K5: GroupNorm + affine + residual ----------------
__global__ __launch_bounds__(256) void k_norm(
    const float* __restrict__ Z, const float* __restrict__ x,
    const float* __restrict__ gamma, const float* __restrict__ beta,
    const float* __restrict__ SUMS, float* __restrict__ out) {
  int idx = blockIdx.x * 256 + threadIdx.x;
  size_t f = (size_t)idx * 4;
  int c = (int)((f >> 11) & (Cn - 1));
  int b = (int)(f >> 19);
  int bg = b * 4 + (c >> 6);
  const float inv = 1.f / 131072.f;
  float mean = SUMS[bg * 2] * inv;
  float var = SUMS[bg * 2 + 1] * inv - mean * mean;
  float rstd = rsqrtf(var + EPSf);
  float ga = gamma[c] * rstd;
  float be = beta[c] - mean * ga;
  float4 zv = *(const float4*)(Z + f);
  float4 xv = *(const float4*)(x + f);
  float4 o;
  o.x = zv.x * ga + be + xv.x;
  o.y = zv.y * ga + be + xv.y;
  o.z = zv.z * ga + be + xv.z;
  o.w = zv.w * ga + be + xv.w;
  *(float4*)(out + f) = o;
}

extern "C" void kernel_launch(void* const* d_in, const int* in_sizes, int n_in,
                              void* d_out, int out_size, void* d_ws, size_t ws_size,
                              hipStream_t stream) {
  (void)in_sizes; (void)n_in; (void)out_size; (void)ws_size;
  const float* x = (const float*)d_in[0];
  const float* y = (const float*)d_in[1];
  const float* Wt = (const float*)d_in[2];
  const float* Wp = (const float*)d_in[3];
  const float* Wg = (const float*)d_in[4];
  const float* Wz = (const float*)d_in[5];
  const float* gamma = (const float*)d_in[6];
  const float* beta = (const float*)d_in[7];
  float* out = (float*)d_out;
  char* ws = (char*)d_ws;
  unsigned short* wpb = (unsigned short*)(ws + 0);
  unsigned short* wtb = (unsigned short*)(ws + 131072);
  unsigned short* wgb = (unsigned short*)(ws + 262144);
  unsigned short* wzb = (unsigned short*)(ws + 393216);
  unsigned short* xt  = (unsigned short*)(ws + 425984);    // 4MB
  unsigned short* yt  = (unsigned short*)(ws + 4620288);   // 4MB
  unsigned short* Pq  = (unsigned short*)(ws + 8814592);   // 4MB
  unsigned short* Tv  = (unsigned short*)(ws + 13008896);  // 4MB
  unsigned short* Gt  = (unsigned short*)(ws + 17203200);  // 4MB
  unsigned short* OT  = (unsigned short*)(ws + 21397504);  // 4MB
  float* Z    = (float*)(ws + 425984);   // overlaps xt/yt (dead after k_mix)
  float* SUMS = (float*)(ws + 25591808);

  k_wconv<<<256, 256, 0, stream>>>(Wt, Wp, Wg, Wz, wtb, wpb, wgb, wzb);
  k_transpose<<<2048, 256, 0, stream>>>(x, y, xt, yt);
  k_mix<<<dim3(32, 2, 12), 256, 0, stream>>>(xt, yt, wpb, wtb, wgb, Pq, Tv, Gt);
  k_attn<<<512, 256, 0, stream>>>(Pq, Tv, Gt, OT);
  (void)hipMemsetAsync(SUMS, 0, 128, stream);
  k_zconv<<<dim3(8, 16), 256, 0, stream>>>(wzb, OT, Z, SUMS);
  k_norm<<<2048, 256, 0, stream>>>(Z, x, gamma, beta, SUMS, out);
}

// Round 6
// 81.813 us; speedup vs baseline: 2.3205x; 1.3040x over previous
//
#include <hip/hip_runtime.h>

typedef __attribute__((ext_vector_type(8))) short short8;
typedef __bf16 bf16x8 __attribute__((ext_vector_type(8)));
typedef __attribute__((ext_vector_type(4))) float f32x4;

static constexpr int Cn = 256, Nn = 2048;
static constexpr float EPSf = 1e-5f;
static constexpr float LOG2E = 1.44269504088896f;

#define DEV __device__ __forceinline__

DEV unsigned short f2bf(float f) { return __builtin_bit_cast(unsigned short, (__bf16)f); }
DEV float bf2f(unsigned u16) { return __builtin_bit_cast(float, u16 << 16); }
DEV unsigned pk2bf(float a, float b) {
  return (unsigned)f2bf(a) | ((unsigned)f2bf(b) << 16);
}
DEV f32x4 mfma16(short8 a, short8 b, f32x4 c) {
  return __builtin_amdgcn_mfma_f32_16x16x32_bf16(
      __builtin_bit_cast(bf16x8, a), __builtin_bit_cast(bf16x8, b), c, 0, 0, 0);
}
DEV short8 ld8(const unsigned short* p) { return *(const short8*)p; }

// ---------------- K1: fused convert+transpose+channel-mix GEMMs ----------------
// Reads x,y,W in ORIGINAL f32 layouts; stages tiles through LDS (bf16,
// transposed in-LDS for B). op0: P=Wp*x, op1: T=Wt*y, op2: Gt=Wg*y (*LOG2E,
// stored [bg][j][c] for attention K-fragments). Rows padded to 40 ushorts
// (80B) so all b128 fragment reads hit the uniform 8-lanes-per-16B-group floor.
// Also zeroes SUMS (block (0,0,0)) for k_zconv's atomics.
__global__ __launch_bounds__(256) void k_mix(
    const float* __restrict__ x, const float* __restrict__ y,
    const float* __restrict__ Wp, const float* __restrict__ Wt,
    const float* __restrict__ Wg, unsigned short* __restrict__ P,
    unsigned short* __restrict__ T, unsigned short* __restrict__ Gt,
    float* __restrict__ SUMS) {
  __shared__ __align__(16) unsigned short lds[7680];  // As[128][40] + Bs[64][40]

  int t = threadIdx.x, lane = t & 63, w = t >> 6;
  int q = lane >> 4, li = lane & 15;
  int zb = blockIdx.z, b = zb & 3, op = zb >> 2;
  const float* in = (op == 0 ? x : y) + (size_t)b * Cn * Nn;
  const float* W = (op == 0 ? Wp : (op == 1 ? Wt : Wg));
  int p0 = blockIdx.y * 128, h0 = blockIdx.x * 64;
  if (blockIdx.x == 0 && blockIdx.y == 0 && zb == 0 && t < 32) SUMS[t] = 0.f;

  int arow = t >> 3, ac4 = t & 7;    // A: 32 rows x 8 float4-cols per pass
  int bc = t >> 4, bh4 = t & 15;     // B: 16 c-rows x 16 float4-cols per pass
  float4 wv[4], bv[2];
#pragma unroll
  for (int i2 = 0; i2 < 4; ++i2)
    wv[i2] = *(const float4*)&W[(size_t)(p0 + i2 * 32 + arow) * 256 + ac4 * 4];
#pragma unroll
  for (int i2 = 0; i2 < 2; ++i2)
    bv[i2] = *(const float4*)&in[(size_t)(i2 * 16 + bc) * Nn + h0 + bh4 * 4];

  f32x4 acc[2][4] = {};
  for (int kk = 0; kk < 8; ++kk) {
    __syncthreads();  // previous compute done before LDS overwrite
#pragma unroll
    for (int i2 = 0; i2 < 4; ++i2)
      *(uint2*)&lds[(i2 * 32 + arow) * 40 + ac4 * 4] =
          make_uint2(pk2bf(wv[i2].x, wv[i2].y), pk2bf(wv[i2].z, wv[i2].w));
#pragma unroll
    for (int i2 = 0; i2 < 2; ++i2) {
      int cL = i2 * 16 + bc, hL = bh4 * 4;
      lds[5120 + (hL + 0) * 40 + cL] = f2bf(bv[i2].x);
      lds[5120 + (hL + 1) * 40 + cL] = f2bf(bv[i2].y);
      lds[5120 + (hL + 2) * 40 + cL] = f2bf(bv[i2].z);
      lds[5120 + (hL + 3) * 40 + cL] = f2bf(bv[i2].w);
    }
    if (kk < 7) {
      int k1 = (kk + 1) * 32;
#pragma unroll
      for (int i2 = 0; i2 < 4; ++i2)
        wv[i2] = *(const float4*)&W[(size_t)(p0 + i2 * 32 + arow) * 256 + k1 + ac4 * 4];
#pragma unroll
      for (int i2 = 0; i2 < 2; ++i2)
        bv[i2] = *(const float4*)&in[(size_t)(k1 + i2 * 16 + bc) * Nn + h0 + bh4 * 4];
    }
    __syncthreads();
    int pw = w * 32;
    short8 a0 = *(const short8*)&lds[(pw + li) * 40 + q * 8];
    short8 a1 = *(const short8*)&lds[(pw + 16 + li) * 40 + q * 8];
#pragma unroll
    for (int nt = 0; nt < 4; ++nt) {
      short8 bfr = *(const short8*)&lds[5120 + (nt * 16 + li) * 40 + q * 8];
      acc[0][nt] = mfma16(a0, bfr, acc[0][nt]);
      acc[1][nt] = mfma16(a1, bfr, acc[1][nt]);
    }
  }
  int pbase = p0 + w * 32;
  if (op < 2) {
    unsigned short* dst = (op == 0 ? P : T) + (size_t)b * Cn * Nn;
#pragma unroll
    for (int mt = 0; mt < 2; ++mt)
#pragma unroll
      for (int nt = 0; nt < 4; ++nt)
#pragma unroll
        for (int r = 0; r < 4; ++r)
          dst[(size_t)(pbase + mt * 16 + q * 4 + r) * Nn + h0 + nt * 16 + li] =
              f2bf(acc[mt][nt][r]);
  } else {
#pragma unroll
    for (int mt = 0; mt < 2; ++mt)
#pragma unroll
      for (int nt = 0; nt < 4; ++nt)
#pragma unroll
        for (int r = 0; r < 4; ++r) {
          int c = pbase + mt * 16 + q * 4 + r;
          int h = h0 + nt * 16 + li;
          Gt[(((size_t)(b * 4 + (c >> 6)) * Nn + h) << 6) + (c & 63)] =
              f2bf(acc[mt][nt][r] * LOG2E);
        }
  }
}

// ---------------- K3: attention, 128 q-rows/block (32 per wave) ----------------
// Grid 256 = 1 block/CU, 32/XCD (pinned via bid&7). K/V LDS fragments are
// shared across both q-sets AND all 4 waves -> LDS traffic per q-row halved
// vs 16-row waves. No-max softmax (bounded scores), register prefetch of the
// next K/V tile hides L2 latency under compute.
__global__ __launch_bounds__(256) void k_attn(
    const unsigned short* __restrict__ Pq, const unsigned short* __restrict__ Tv,
    const unsigned short* __restrict__ Gt, unsigned short* __restrict__ OT) {
  __shared__ __align__(16) unsigned short lds[16384];  // Ks 8KB | Vs 8KB | P 16KB

  int t = threadIdx.x, lane = t & 63, w = t >> 6;
  int q = lane >> 4, li = lane & 15;
  int bid = blockIdx.x;
  int xcd = bid & 7, slot = bid >> 3;        // 32 slots per XCD
  int bg = xcd * 2 + (slot >> 4);            // 2 heads per XCD (L2-resident)
  int i0 = (slot & 15) * 128;
  int b = bg >> 2, g = bg & 3;
  const unsigned short* Q = Pq + (size_t)(b * Cn + g * 64) * Nn;
  const unsigned short* V = Tv + (size_t)(b * Cn + g * 64) * Nn;
  const unsigned short* Kk = Gt + (size_t)bg * Nn * 64;

  int iw = i0 + w * 32;  // wave's 32 q-rows (2 sets of 16)
  short8 qf[2][2];
#pragma unroll
  for (int s = 0; s < 2; ++s)
#pragma unroll
    for (int cs = 0; cs < 2; ++cs) {
      short8 v;
#pragma unroll
      for (int e = 0; e < 8; ++e)
        v[e] = (short)Q[(size_t)(cs * 32 + q * 8 + e) * Nn + iw + s * 16 + li];
      qf[s][cs] = v;
    }
  f32x4 O[2][4] = {};
  float rs[2] = {0.f, 0.f};

  int srow = t >> 2, soff0 = (t & 3) * 2;  // staging: 16B chunks, coalesced
  short8 kst[2], vst[2];
#pragma unroll
  for (int u = 0; u < 2; ++u) {
    kst[u] = ld8(Kk + (size_t)srow * 64 + (soff0 + u) * 8);
    vst[u] = ld8(V + (size_t)srow * Nn + (soff0 + u) * 8);
  }

  for (int jt32 = 0; jt32 < 32; ++jt32) {
    __syncthreads();
#pragma unroll
    for (int u = 0; u < 2; ++u) {
      int sl = (soff0 + u) ^ (srow & 7);
      *(short8*)&lds[srow * 64 + sl * 8] = kst[u];
      *(short8*)&lds[4096 + srow * 64 + sl * 8] = vst[u];
    }
    if (jt32 < 31) {
      int j1 = (jt32 + 1) * 64;
#pragma unroll
      for (int u = 0; u < 2; ++u) {
        kst[u] = ld8(Kk + (size_t)(j1 + srow) * 64 + (soff0 + u) * 8);
        vst[u] = ld8(V + (size_t)srow * Nn + j1 + (soff0 + u) * 8);
      }
    }
    __syncthreads();

    f32x4 F[2][4] = {};
#pragma unroll
    for (int jt = 0; jt < 4; ++jt) {
      int row = jt * 16 + li;
      short8 k0 = *(const short8*)&lds[row * 64 + ((q) ^ (row & 7)) * 8];
      short8 k1 = *(const short8*)&lds[row * 64 + ((4 + q) ^ (row & 7)) * 8];
      F[0][jt] = mfma16(k0, qf[0][0], F[0][jt]);
      F[0][jt] = mfma16(k1, qf[0][1], F[0][jt]);
      F[1][jt] = mfma16(k0, qf[1][0], F[1][jt]);
      F[1][jt] = mfma16(k1, qf[1][1], F[1][jt]);
    }
#pragma unroll
    for (int s = 0; s < 2; ++s)
#pragma unroll
      for (int jt = 0; jt < 4; ++jt) {
        float e0 = __builtin_amdgcn_exp2f(F[s][jt][0]);
        float e1 = __builtin_amdgcn_exp2f(F[s][jt][1]);
        float e2 = __builtin_amdgcn_exp2f(F[s][jt][2]);
        float e3 = __builtin_amdgcn_exp2f(F[s][jt][3]);
        rs[s] += (e0 + e1) + (e2 + e3);
        *(uint2*)&lds[8192 + (w * 32 + s * 16 + li) * 64 +
                      ((jt * 2 + (q >> 1)) ^ (li & 7)) * 8 + (q & 1) * 4] =
            make_uint2(pk2bf(e0, e1), pk2bf(e2, e3));
      }
#pragma unroll
    for (int cs = 0; cs < 2; ++cs) {
      short8 pf0 = *(const short8*)&lds[8192 + (w * 32 + li) * 64 +
                                        ((cs * 4 + q) ^ (li & 7)) * 8];
      short8 pf1 = *(const short8*)&lds[8192 + (w * 32 + 16 + li) * 64 +
                                        ((cs * 4 + q) ^ (li & 7)) * 8];
#pragma unroll
      for (int ct = 0; ct < 4; ++ct) {
        int row = ct * 16 + li;
        short8 vf =
            *(const short8*)&lds[4096 + row * 64 + ((cs * 4 + q) ^ (row & 7)) * 8];
        O[0][ct] = mfma16(pf0, vf, O[0][ct]);
        O[1][ct] = mfma16(pf1, vf, O[1][ct]);
      }
    }
  }
  unsigned short* op = OT + (size_t)bg * Nn * 64;
#pragma unroll
  for (int s = 0; s < 2; ++s) {
    float r = rs[s];
    r += __shfl_xor(r, 16);
    r += __shfl_xor(r, 32);
    float r0 = 1.f / __shfl(r, q * 4 + 0);
    float r1 = 1.f / __shfl(r, q * 4 + 1);
    float r2 = 1.f / __shfl(r, q * 4 + 2);
    float r3 = 1.f / __shfl(r, q * 4 + 3);
#pragma unroll
    for (int ct = 0; ct < 4; ++ct) {
      op[(size_t)(iw + s * 16 + q * 4 + 0) * 64 + ct * 16 + li] = f2bf(O[s][ct][0] * r0);
      op[(size_t)(iw + s * 16 + q * 4 + 1) * 64 + ct * 16 + li] = f2bf(O[s][ct][1] * r1);
      op[(size_t)(iw + s * 16 + q * 4 + 2) * 64 + ct * 16 + li] = f2bf(O[s][ct][2] * r2);
      op[(size_t)(iw + s * 16 + q * 4 + 3) * 64 + ct * 16 + li] = f2bf(O[s][ct][3] * r3);
    }
  }
}

// ---------------- K4: grouped 1x1 conv + group sum/sumsq (LDS-staged) ----------
// OT tile is CONTIGUOUS [128h][64c] -> linear coalesced stage + swizzled reads.
// Wz converted f32->bf16 during staging. Z emitted as bf16.
__global__ __launch_bounds__(256) void k_zconv(
    const float* __restrict__ Wz, const unsigned short* __restrict__ OT,
    unsigned short* __restrict__ Zb, float* __restrict__ SUMS) {
  __shared__ __align__(16) unsigned short lds[12288];  // OTs[128][64] | Wzs[64][64]
  int t = threadIdx.x, lane = t & 63, w = t >> 6;
  int q = lane >> 4, li = lane & 15;
  int bg = blockIdx.y, b = bg >> 2, g = bg & 3;
  int i0 = blockIdx.x * 128;
  const unsigned short* region = OT + ((size_t)bg * Nn + i0) * 64;
#pragma unroll
  for (int p = 0; p < 4; ++p) {
    int chunk = p * 256 + t;
    int row = chunk >> 3, sl = chunk & 7;
    short8 v = ld8(region + row * 64 + sl * 8);
    *(short8*)&lds[row * 64 + (sl ^ (row & 7)) * 8] = v;
  }
  const float* Wg2 = Wz + g * 64 * 64;
#pragma unroll
  for (int p = 0; p < 4; ++p) {
    int o = p * 16 + (t >> 4), f4c = t & 15;
    float4 v = *(const float4*)&Wg2[o * 64 + f4c * 4];
    *(uint2*)&lds[8192 + o * 64 + ((f4c >> 1) ^ (o & 7)) * 8 + (f4c & 1) * 4] =
        make_uint2(pk2bf(v.x, v.y), pk2bf(v.z, v.w));
  }
  __syncthreads();
  f32x4 acc[4][2] = {};
#pragma unroll
  for (int cs = 0; cs < 2; ++cs) {
    short8 af[4];
#pragma unroll
    for (int mt = 0; mt < 4; ++mt) {
      int orow = mt * 16 + li;
      af[mt] = *(const short8*)&lds[8192 + orow * 64 + ((cs * 4 + q) ^ (orow & 7)) * 8];
    }
#pragma unroll
    for (int nt = 0; nt < 2; ++nt) {
      int hrow = w * 32 + nt * 16 + li;
      short8 bfr = *(const short8*)&lds[hrow * 64 + ((cs * 4 + q) ^ (hrow & 7)) * 8];
#pragma unroll
      for (int mt = 0; mt < 4; ++mt) acc[mt][nt] = mfma16(af[mt], bfr, acc[mt][nt]);
    }
  }
  float s1 = 0.f, s2 = 0.f;
  unsigned short* zb = Zb + (size_t)(b * Cn + g * 64) * Nn;
#pragma unroll
  for (int mt = 0; mt < 4; ++mt)
#pragma unroll
    for (int nt = 0; nt < 2; ++nt)
#pragma unroll
      for (int r = 0; r < 4; ++r) {
        float v = acc[mt][nt][r];
        s1 += v; s2 += v * v;
        zb[(size_t)(mt * 16 + q * 4 + r) * Nn + i0 + w * 32 + nt * 16 + li] = f2bf(v);
      }
#pragma unroll
  for (int off = 32; off; off >>= 1) {
    s1 += __shfl_xor(s1, off);
    s2 += __shfl_xor(s2, off);
  }
  if (lane == 0) {
    atomicAdd(&SUMS[bg * 2], s1);
    atomicAdd(&SUMS[bg * 2 + 1], s2);
  }
}

// ---------------- K5: GroupNorm + affine + residual ----------------
__global__ __launch_bounds__(256) void k_norm(
    const unsigned short* __restrict__ Zb, const float* __restrict__ x,
    const float* __restrict__ gamma, const float* __restrict__ beta,
    const float* __restrict__ SUMS, float* __restrict__ out) {
  int idx = blockIdx.x * 256 + threadIdx.x;
  size_t f = (size_t)idx * 4;
  int c = (int)((f >> 11) & (Cn - 1));
  int b = (int)(f >> 19);
  int bg = b * 4 + (c >> 6);
  const float inv = 1.f / 131072.f;
  float mean = SUMS[bg * 2] * inv;
  float var = SUMS[bg * 2 + 1] * inv - mean * mean;
  float rstd = rsqrtf(var + EPSf);
  float ga = gamma[c] * rstd;
  float be = beta[c] - mean * ga;
  uint2 u = *(const uint2*)&Zb[f];
  float4 xv = *(const float4*)(x + f);
  float4 o;
  o.x = bf2f(u.x & 0xffffu) * ga + be + xv.x;
  o.y = bf2f(u.x >> 16) * ga + be + xv.y;
  o.z = bf2f(u.y & 0xffffu) * ga + be + xv.z;
  o.w = bf2f(u.y >> 16) * ga + be + xv.w;
  *(float4*)(out + f) = o;
}

extern "C" void kernel_launch(void* const* d_in, const int* in_sizes, int n_in,
                              void* d_out, int out_size, void* d_ws, size_t ws_size,
                              hipStream_t stream) {
  (void)in_sizes; (void)n_in; (void)out_size; (void)ws_size;
  const float* x = (const float*)d_in[0];
  const float* y = (const float*)d_in[1];
  const float* Wt = (const float*)d_in[2];
  const float* Wp = (const float*)d_in[3];
  const float* Wg = (const float*)d_in[4];
  const float* Wz = (const float*)d_in[5];
  const float* gamma = (const float*)d_in[6];
  const float* beta = (const float*)d_in[7];
  float* out = (float*)d_out;
  char* ws = (char*)d_ws;
  unsigned short* Pq = (unsigned short*)(ws + 0);
  unsigned short* Tv = (unsigned short*)(ws + 4194304);
  unsigned short* Gt = (unsigned short*)(ws + 8388608);
  unsigned short* OT = (unsigned short*)(ws + 12582912);
  unsigned short* Zb = (unsigned short*)(ws + 16777216);
  float* SUMS = (float*)(ws + 20971520);

  k_mix<<<dim3(32, 2, 12), 256, 0, stream>>>(x, y, Wp, Wt, Wg, Pq, Tv, Gt, SUMS);
  k_attn<<<256, 256, 0, stream>>>(Pq, Tv, Gt, OT);
  k_zconv<<<dim3(16, 16), 256, 0, stream>>>(Wz, OT, Zb, SUMS);
  k_norm<<<2048, 256, 0, stream>>>(Zb, x, gamma, beta, SUMS, out);
}

// Round 7
// 76.145 us; speedup vs baseline: 2.4933x; 1.0744x over previous
//
#include <hip/hip_runtime.h>

typedef __attribute__((ext_vector_type(8))) short short8;
typedef __bf16 bf16x8 __attribute__((ext_vector_type(8)));
typedef __attribute__((ext_vector_type(4))) float f32x4;

static constexpr int Cn = 256, Nn = 2048;
static constexpr float EPSf = 1e-5f;
static constexpr float LOG2E = 1.44269504088896f;

#define DEV __device__ __forceinline__

DEV unsigned short f2bf(float f) { return __builtin_bit_cast(unsigned short, (__bf16)f); }
DEV float bf2f(unsigned u16) { return __builtin_bit_cast(float, u16 << 16); }
DEV unsigned pk2bf(float a, float b) {
  return (unsigned)f2bf(a) | ((unsigned)f2bf(b) << 16);
}
DEV f32x4 mfma16(short8 a, short8 b, f32x4 c) {
  return __builtin_amdgcn_mfma_f32_16x16x32_bf16(
      __builtin_bit_cast(bf16x8, a), __builtin_bit_cast(bf16x8, b), c, 0, 0, 0);
}
DEV short8 ld8(const unsigned short* p) { return *(const short8*)p; }

// ---------------- K1: fused convert+transpose+channel-mix GEMMs ----------------
__global__ __launch_bounds__(256) void k_mix(
    const float* __restrict__ x, const float* __restrict__ y,
    const float* __restrict__ Wp, const float* __restrict__ Wt,
    const float* __restrict__ Wg, unsigned short* __restrict__ P,
    unsigned short* __restrict__ T, unsigned short* __restrict__ Gt,
    float* __restrict__ SUMS) {
  __shared__ __align__(16) unsigned short lds[7680];  // As[128][40] + Bs[64][40]

  int t = threadIdx.x, lane = t & 63, w = t >> 6;
  int q = lane >> 4, li = lane & 15;
  int zb = blockIdx.z, b = zb & 3, op = zb >> 2;
  const float* in = (op == 0 ? x : y) + (size_t)b * Cn * Nn;
  const float* W = (op == 0 ? Wp : (op == 1 ? Wt : Wg));
  int p0 = blockIdx.y * 128, h0 = blockIdx.x * 64;
  if (blockIdx.x == 0 && blockIdx.y == 0 && zb == 0 && t < 32) SUMS[t] = 0.f;

  int arow = t >> 3, ac4 = t & 7;
  int bc = t >> 4, bh4 = t & 15;
  float4 wv[4], bv[2];
#pragma unroll
  for (int i2 = 0; i2 < 4; ++i2)
    wv[i2] = *(const float4*)&W[(size_t)(p0 + i2 * 32 + arow) * 256 + ac4 * 4];
#pragma unroll
  for (int i2 = 0; i2 < 2; ++i2)
    bv[i2] = *(const float4*)&in[(size_t)(i2 * 16 + bc) * Nn + h0 + bh4 * 4];

  f32x4 acc[2][4] = {};
  for (int kk = 0; kk < 8; ++kk) {
    __syncthreads();
#pragma unroll
    for (int i2 = 0; i2 < 4; ++i2)
      *(uint2*)&lds[(i2 * 32 + arow) * 40 + ac4 * 4] =
          make_uint2(pk2bf(wv[i2].x, wv[i2].y), pk2bf(wv[i2].z, wv[i2].w));
#pragma unroll
    for (int i2 = 0; i2 < 2; ++i2) {
      int cL = i2 * 16 + bc, hL = bh4 * 4;
      lds[5120 + (hL + 0) * 40 + cL] = f2bf(bv[i2].x);
      lds[5120 + (hL + 1) * 40 + cL] = f2bf(bv[i2].y);
      lds[5120 + (hL + 2) * 40 + cL] = f2bf(bv[i2].z);
      lds[5120 + (hL + 3) * 40 + cL] = f2bf(bv[i2].w);
    }
    if (kk < 7) {
      int k1 = (kk + 1) * 32;
#pragma unroll
      for (int i2 = 0; i2 < 4; ++i2)
        wv[i2] = *(const float4*)&W[(size_t)(p0 + i2 * 32 + arow) * 256 + k1 + ac4 * 4];
#pragma unroll
      for (int i2 = 0; i2 < 2; ++i2)
        bv[i2] = *(const float4*)&in[(size_t)(k1 + i2 * 16 + bc) * Nn + h0 + bh4 * 4];
    }
    __syncthreads();
    int pw = w * 32;
    short8 a0 = *(const short8*)&lds[(pw + li) * 40 + q * 8];
    short8 a1 = *(const short8*)&lds[(pw + 16 + li) * 40 + q * 8];
#pragma unroll
    for (int nt = 0; nt < 4; ++nt) {
      short8 bfr = *(const short8*)&lds[5120 + (nt * 16 + li) * 40 + q * 8];
      acc[0][nt] = mfma16(a0, bfr, acc[0][nt]);
      acc[1][nt] = mfma16(a1, bfr, acc[1][nt]);
    }
  }
  int pbase = p0 + w * 32;
  if (op < 2) {
    unsigned short* dst = (op == 0 ? P : T) + (size_t)b * Cn * Nn;
#pragma unroll
    for (int mt = 0; mt < 2; ++mt)
#pragma unroll
      for (int nt = 0; nt < 4; ++nt)
#pragma unroll
        for (int r = 0; r < 4; ++r)
          dst[(size_t)(pbase + mt * 16 + q * 4 + r) * Nn + h0 + nt * 16 + li] =
              f2bf(acc[mt][nt][r]);
  } else {
#pragma unroll
    for (int mt = 0; mt < 2; ++mt)
#pragma unroll
      for (int nt = 0; nt < 4; ++nt)
#pragma unroll
        for (int r = 0; r < 4; ++r) {
          int c = pbase + mt * 16 + q * 4 + r;
          int h = h0 + nt * 16 + li;
          Gt[(((size_t)(b * 4 + (c >> 6)) * Nn + h) << 6) + (c & 63)] =
              f2bf(acc[mt][nt][r] * LOG2E);
        }
  }
}

// ---------------- K3: attention, dbuf K/V, ONE barrier per 64-j tile ----------
// 512 blocks = 2/CU (barrier stalls of one block overlap the other's compute).
// Iter t: write staged regs -> buf[t&1]; prefetch tile t+1 to regs; compute
// tile t-1 from buf[(t-1)&1]. The single __syncthreads (drains lgkmcnt)
// guarantees both visibility and WAR safety. LDS 40KB/block.
__global__ __launch_bounds__(256) void k_attn(
    const unsigned short* __restrict__ Pq, const unsigned short* __restrict__ Tv,
    const unsigned short* __restrict__ Gt, unsigned short* __restrict__ OT) {
  __shared__ __align__(16) unsigned short lds[20480];  // K dbuf 2x8KB | V dbuf 2x8KB | P 8KB

  int t = threadIdx.x, lane = t & 63, w = t >> 6;
  int q = lane >> 4, li = lane & 15;
  int bid = blockIdx.x;
  int xcd = bid & 7, slot = bid >> 3;        // 64 slots per XCD
  int bg = xcd * 2 + (slot >> 5);            // 2 heads per XCD (L2-resident)
  int i0 = (slot & 31) * 64;
  int b = bg >> 2, g = bg & 3;
  const unsigned short* Q = Pq + (size_t)(b * Cn + g * 64) * Nn;
  const unsigned short* V = Tv + (size_t)(b * Cn + g * 64) * Nn;
  const unsigned short* Kk = Gt + (size_t)bg * Nn * 64;

  int iw = i0 + w * 16;  // this wave's 16 q-rows
  short8 qf[2];
#pragma unroll
  for (int cs = 0; cs < 2; ++cs) {
    short8 v;
#pragma unroll
    for (int e = 0; e < 8; ++e)
      v[e] = (short)Q[(size_t)(cs * 32 + q * 8 + e) * Nn + iw + li];
    qf[cs] = v;
  }
  f32x4 O[4] = {};
  float rs = 0.f;

  int srow = t >> 2, soff0 = (t & 3) * 2;  // staging: coalesced 16B chunks
  short8 kst[2], vst[2];
#pragma unroll
  for (int u = 0; u < 2; ++u) {
    kst[u] = ld8(Kk + (size_t)srow * 64 + (soff0 + u) * 8);
    vst[u] = ld8(V + (size_t)srow * Nn + (soff0 + u) * 8);
  }

  auto compute = [&](int kb, int j0unused) {
    int vb = kb + 8192;
    f32x4 F[4] = {};
#pragma unroll
    for (int jt = 0; jt < 4; ++jt) {
      int row = jt * 16 + li;
      short8 k0 = *(const short8*)&lds[kb + row * 64 + ((q) ^ (row & 7)) * 8];
      short8 k1 = *(const short8*)&lds[kb + row * 64 + ((4 + q) ^ (row & 7)) * 8];
      F[jt] = mfma16(k0, qf[0], F[jt]);
      F[jt] = mfma16(k1, qf[1], F[jt]);
    }
#pragma unroll
    for (int jt = 0; jt < 4; ++jt) {
      float e0 = __builtin_amdgcn_exp2f(F[jt][0]);
      float e1 = __builtin_amdgcn_exp2f(F[jt][1]);
      float e2 = __builtin_amdgcn_exp2f(F[jt][2]);
      float e3 = __builtin_amdgcn_exp2f(F[jt][3]);
      rs += (e0 + e1) + (e2 + e3);
      *(uint2*)&lds[16384 + (w * 16 + li) * 64 +
                    ((jt * 2 + (q >> 1)) ^ (li & 7)) * 8 + (q & 1) * 4] =
          make_uint2(pk2bf(e0, e1), pk2bf(e2, e3));
    }
#pragma unroll
    for (int cs = 0; cs < 2; ++cs) {
      short8 pf = *(const short8*)&lds[16384 + (w * 16 + li) * 64 +
                                       ((cs * 4 + q) ^ (li & 7)) * 8];
#pragma unroll
      for (int ct = 0; ct < 4; ++ct) {
        int row = ct * 16 + li;
        short8 vf =
            *(const short8*)&lds[vb + row * 64 + ((cs * 4 + q) ^ (row & 7)) * 8];
        O[ct] = mfma16(pf, vf, O[ct]);
      }
    }
  };

  for (int jt32 = 0; jt32 < 32; ++jt32) {
    int cur = (jt32 & 1) * 4096;
    __syncthreads();
#pragma unroll
    for (int u = 0; u < 2; ++u) {
      int sl = (soff0 + u) ^ (srow & 7);
      *(short8*)&lds[cur + srow * 64 + sl * 8] = kst[u];
      *(short8*)&lds[8192 + cur + srow * 64 + sl * 8] = vst[u];
    }
    if (jt32 < 31) {
      int j1 = (jt32 + 1) * 64;
#pragma unroll
      for (int u = 0; u < 2; ++u) {
        kst[u] = ld8(Kk + (size_t)(j1 + srow) * 64 + (soff0 + u) * 8);
        vst[u] = ld8(V + (size_t)srow * Nn + j1 + (soff0 + u) * 8);
      }
    }
    if (jt32 > 0) compute(cur ^ 4096, 0);
  }
  __syncthreads();
  compute(4096, 0);  // tile 31 lives in buf 1

  rs += __shfl_xor(rs, 16);
  rs += __shfl_xor(rs, 32);
  float r0 = 1.f / __shfl(rs, q * 4 + 0);
  float r1 = 1.f / __shfl(rs, q * 4 + 1);
  float r2 = 1.f / __shfl(rs, q * 4 + 2);
  float r3 = 1.f / __shfl(rs, q * 4 + 3);
  unsigned short* op = OT + (size_t)bg * Nn * 64;
#pragma unroll
  for (int ct = 0; ct < 4; ++ct) {
    op[(size_t)(iw + q * 4 + 0) * 64 + ct * 16 + li] = f2bf(O[ct][0] * r0);
    op[(size_t)(iw + q * 4 + 1) * 64 + ct * 16 + li] = f2bf(O[ct][1] * r1);
    op[(size_t)(iw + q * 4 + 2) * 64 + ct * 16 + li] = f2bf(O[ct][2] * r2);
    op[(size_t)(iw + q * 4 + 3) * 64 + ct * 16 + li] = f2bf(O[ct][3] * r3);
  }
}

// ---------------- K4: grouped 1x1 conv + group sum/sumsq (LDS-staged) ----------
__global__ __launch_bounds__(256) void k_zconv(
    const float* __restrict__ Wz, const unsigned short* __restrict__ OT,
    unsigned short* __restrict__ Zb, float* __restrict__ SUMS) {
  __shared__ __align__(16) unsigned short lds[12288];  // OTs[128][64] | Wzs[64][64]
  int t = threadIdx.x, lane = t & 63, w = t >> 6;
  int q = lane >> 4, li = lane & 15;
  int bg = blockIdx.y, b = bg >> 2, g = bg & 3;
  int i0 = blockIdx.x * 128;
  const unsigned short* region = OT + ((size_t)bg * Nn + i0) * 64;
#pragma unroll
  for (int p = 0; p < 4; ++p) {
    int chunk = p * 256 + t;
    int row = chunk >> 3, sl = chunk & 7;
    short8 v = ld8(region + row * 64 + sl * 8);
    *(short8*)&lds[row * 64 + (sl ^ (row & 7)) * 8] = v;
  }
  const float* Wg2 = Wz + g * 64 * 64;
#pragma unroll
  for (int p = 0; p < 4; ++p) {
    int o = p * 16 + (t >> 4), f4c = t & 15;
    float4 v = *(const float4*)&Wg2[o * 64 + f4c * 4];
    *(uint2*)&lds[8192 + o * 64 + ((f4c >> 1) ^ (o & 7)) * 8 + (f4c & 1) * 4] =
        make_uint2(pk2bf(v.x, v.y), pk2bf(v.z, v.w));
  }
  __syncthreads();
  f32x4 acc[4][2] = {};
#pragma unroll
  for (int cs = 0; cs < 2; ++cs) {
    short8 af[4];
#pragma unroll
    for (int mt = 0; mt < 4; ++mt) {
      int orow = mt * 16 + li;
      af[mt] = *(const short8*)&lds[8192 + orow * 64 + ((cs * 4 + q) ^ (orow & 7)) * 8];
    }
#pragma unroll
    for (int nt = 0; nt < 2; ++nt) {
      int hrow = w * 32 + nt * 16 + li;
      short8 bfr = *(const short8*)&lds[hrow * 64 + ((cs * 4 + q) ^ (hrow & 7)) * 8];
#pragma unroll
      for (int mt = 0; mt < 4; ++mt) acc[mt][nt] = mfma16(af[mt], bfr, acc[mt][nt]);
    }
  }
  float s1 = 0.f, s2 = 0.f;
  unsigned short* zb = Zb + (size_t)(b * Cn + g * 64) * Nn;
#pragma unroll
  for (int mt = 0; mt < 4; ++mt)
#pragma unroll
    for (int nt = 0; nt < 2; ++nt)
#pragma unroll
      for (int r = 0; r < 4; ++r) {
        float v = acc[mt][nt][r];
        s1 += v; s2 += v * v;
        zb[(size_t)(mt * 16 + q * 4 + r) * Nn + i0 + w * 32 + nt * 16 + li] = f2bf(v);
      }
#pragma unroll
  for (int off = 32; off; off >>= 1) {
    s1 += __shfl_xor(s1, off);
    s2 += __shfl_xor(s2, off);
  }
  if (lane == 0) {
    atomicAdd(&SUMS[bg * 2], s1);
    atomicAdd(&SUMS[bg * 2 + 1], s2);
  }
}

// ---------------- K5: GroupNorm + affine + residual ----------------
__global__ __launch_bounds__(256) void k_norm(
    const unsigned short* __restrict__ Zb, const float* __restrict__ x,
    const float* __restrict__ gamma, const float* __restrict__ beta,
    const float* __restrict__ SUMS, float* __restrict__ out) {
  int idx = blockIdx.x * 256 + threadIdx.x;
  size_t f = (size_t)idx * 4;
  int c = (int)((f >> 11) & (Cn - 1));
  int b = (int)(f >> 19);
  int bg = b * 4 + (c >> 6);
  const float inv = 1.f / 131072.f;
  float mean = SUMS[bg * 2] * inv;
  float var = SUMS[bg * 2 + 1] * inv - mean * mean;
  float rstd = rsqrtf(var + EPSf);
  float ga = gamma[c] * rstd;
  float be = beta[c] - mean * ga;
  uint2 u = *(const uint2*)&Zb[f];
  float4 xv = *(const float4*)(x + f);
  float4 o;
  o.x = bf2f(u.x & 0xffffu) * ga + be + xv.x;
  o.y = bf2f(u.x >> 16) * ga + be + xv.y;
  o.z = bf2f(u.y & 0xffffu) * ga + be + xv.z;
  o.w = bf2f(u.y >> 16) * ga + be + xv.w;
  *(float4*)(out + f) = o;
}

extern "C" void kernel_launch(void* const* d_in, const int* in_sizes, int n_in,
                              void* d_out, int out_size, void* d_ws, size_t ws_size,
                              hipStream_t stream) {
  (void)in_sizes; (void)n_in; (void)out_size; (void)ws_size;
  const float* x = (const float*)d_in[0];
  const float* y = (const float*)d_in[1];
  const float* Wt = (const float*)d_in[2];
  const float* Wp = (const float*)d_in[3];
  const float* Wg = (const float*)d_in[4];
  const float* Wz = (const float*)d_in[5];
  const float* gamma = (const float*)d_in[6];
  const float* beta = (const float*)d_in[7];
  float* out = (float*)d_out;
  char* ws = (char*)d_ws;
  unsigned short* Pq = (unsigned short*)(ws + 0);
  unsigned short* Tv = (unsigned short*)(ws + 4194304);
  unsigned short* Gt = (unsigned short*)(ws + 8388608);
  unsigned short* OT = (unsigned short*)(ws + 12582912);
  unsigned short* Zb = (unsigned short*)(ws + 16777216);
  float* SUMS = (float*)(ws + 20971520);

  k_mix<<<dim3(32, 2, 12), 256, 0, stream>>>(x, y, Wp, Wt, Wg, Pq, Tv, Gt, SUMS);
  k_attn<<<512, 256, 0, stream>>>(Pq, Tv, Gt, OT);
  k_zconv<<<dim3(16, 16), 256, 0, stream>>>(Wz, OT, Zb, SUMS);
  k_norm<<<2048, 256, 0, stream>>>(Zb, x, gamma, beta, SUMS, out);
}